// Round 3
// baseline (430.927 us; speedup 1.0000x reference)
//
#include <hip/hip_runtime.h>
#include <math.h>

#define N_NODES 50000
#define N_EDGES 1600000
#define HEADS 4
#define HIDDEN 32
#define N_GRAPHS 64
#define NEG_SLOPE 0.2f
#define NT_SCAN ((N_NODES + 255) / 256)   /* 196 */

// ---------------- workspace layout (4-byte units) ----------------
#define OFS_FEAT 0
#define OFS_EL   6400000
#define OFS_ER   6600000
#define OFS_P    6800000
#define OFS_CNT  6850000
#define OFS_OFF  6900000
#define OFS_TS   6950016
#define OFS_SRC  6950272
// total ~34.2 MB

#define GLD16(g, l)                                                            \
  __builtin_amdgcn_global_load_lds(                                            \
      (const __attribute__((address_space(1))) void*)(g),                      \
      (__attribute__((address_space(3))) void*)(l), 16, 0, 0)

// ---------------------------------------------------------------------------
// Kernel 1: feat = features @ W (f32 vector FMA; W + X tile LDS-resident)
// + fused epilogue: el/er attention scores from registers (saves a feat pass)
// block=256: 8 node-groups x 32 col-threads; thread = 4 nodes x 4 cols
// LDS 80KB -> 2 blocks/CU
// NOTE: macro params renamed (A/XS/WV) -- a param named `w` captured the
// member token in `acc.w` and broke compilation last round.
// ---------------------------------------------------------------------------
#define FMA4(A, XS, WV)                                                        \
  A.x = fmaf(XS, WV.x, A.x);                                                   \
  A.y = fmaf(XS, WV.y, A.y);                                                   \
  A.z = fmaf(XS, WV.z, A.z);                                                   \
  A.w = fmaf(XS, WV.w, A.w);

#define DOT4(A, B) ((A).x * (B).x + (A).y * (B).y + (A).z * (B).z + (A).w * (B).w)

__global__ __launch_bounds__(256, 2) void k_gemm(
    const float* __restrict__ X, const float* __restrict__ W,
    const float* __restrict__ attn_l, const float* __restrict__ attn_r,
    float* __restrict__ feat, float* __restrict__ el, float* __restrict__ er) {
  __shared__ float Wl[128 * 128];
  __shared__ float Xl[32 * 128];
  const int t = threadIdx.x;
  const int lane = t & 63;
  const int wave = t >> 6;

  // stage W (64 KB): 64 x 1KB chunks, 16 per wave, lane*16B within chunk
  for (int i = 0; i < 16; ++i) {
    int chunk = i * 4 + wave;
    GLD16(W + chunk * 256 + lane * 4, Wl + chunk * 256);
  }

  const int u = t & 31;      // cols 4u..4u+3
  const int gn = t >> 5;     // node sub-group 0..7 (4 nodes each)
  const int h = u >> 3;      // head of this thread's 4 cols
  const float4 al = *(const float4*)&attn_l[h * 32 + 4 * (u & 7)];
  const float4 ar = *(const float4*)&attn_r[h * 32 + 4 * (u & 7)];
  const int ntiles = (N_NODES + 31) / 32;
  __syncthreads();

  for (int tile = blockIdx.x; tile < ntiles; tile += gridDim.x) {
    const int n0 = tile * 32;
    if (n0 + 32 <= N_NODES) {
      for (int i = 0; i < 4; ++i) {
        int chunk = i * 4 + wave;  // 16 x 1KB
        GLD16(X + n0 * 128 + chunk * 256 + lane * 4, Xl + chunk * 256);
      }
    } else {  // guarded tail tile
      for (int i = t; i < 1024; i += 256) {
        int row = i >> 5, kq = i & 31;
        float4 v = make_float4(0.f, 0.f, 0.f, 0.f);
        if (n0 + row < N_NODES)
          v = ((const float4*)(X + (size_t)(n0 + row) * 128))[kq];
        ((float4*)Xl)[i] = v;
      }
    }
    __syncthreads();

    float4 a0 = make_float4(0.f, 0.f, 0.f, 0.f);
    float4 a1 = a0, a2 = a0, a3 = a0;
#pragma unroll 4
    for (int k = 0; k < 128; k += 4) {
      float4 w0 = *(const float4*)&Wl[(k + 0) * 128 + 4 * u];
      float4 w1 = *(const float4*)&Wl[(k + 1) * 128 + 4 * u];
      float4 w2 = *(const float4*)&Wl[(k + 2) * 128 + 4 * u];
      float4 w3 = *(const float4*)&Wl[(k + 3) * 128 + 4 * u];
      float4 x0 = *(const float4*)&Xl[(gn * 4 + 0) * 128 + k];
      float4 x1 = *(const float4*)&Xl[(gn * 4 + 1) * 128 + k];
      float4 x2 = *(const float4*)&Xl[(gn * 4 + 2) * 128 + k];
      float4 x3 = *(const float4*)&Xl[(gn * 4 + 3) * 128 + k];
      FMA4(a0, x0.x, w0) FMA4(a0, x0.y, w1) FMA4(a0, x0.z, w2) FMA4(a0, x0.w, w3)
      FMA4(a1, x1.x, w0) FMA4(a1, x1.y, w1) FMA4(a1, x1.z, w2) FMA4(a1, x1.w, w3)
      FMA4(a2, x2.x, w0) FMA4(a2, x2.y, w1) FMA4(a2, x2.z, w2) FMA4(a2, x2.w, w3)
      FMA4(a3, x3.x, w0) FMA4(a3, x3.y, w1) FMA4(a3, x3.z, w2) FMA4(a3, x3.w, w3)
    }
    const int nb = n0 + gn * 4;
    if (nb + 0 < N_NODES) *(float4*)&feat[(size_t)(nb + 0) * 128 + 4 * u] = a0;
    if (nb + 1 < N_NODES) *(float4*)&feat[(size_t)(nb + 1) * 128 + 4 * u] = a1;
    if (nb + 2 < N_NODES) *(float4*)&feat[(size_t)(nb + 2) * 128 + 4 * u] = a2;
    if (nb + 3 < N_NODES) *(float4*)&feat[(size_t)(nb + 3) * 128 + 4 * u] = a3;

    // fused el/er: partial dot over this thread's 4 cols, reduce across the
    // 8 lanes (u&7) sharing (node, head) -- contiguous lanes within one wave.
    float pl0 = DOT4(a0, al), pl1 = DOT4(a1, al), pl2 = DOT4(a2, al), pl3 = DOT4(a3, al);
    float pr0 = DOT4(a0, ar), pr1 = DOT4(a1, ar), pr2 = DOT4(a2, ar), pr3 = DOT4(a3, ar);
#pragma unroll
    for (int m = 1; m < 8; m <<= 1) {
      pl0 += __shfl_xor(pl0, m, 64); pl1 += __shfl_xor(pl1, m, 64);
      pl2 += __shfl_xor(pl2, m, 64); pl3 += __shfl_xor(pl3, m, 64);
      pr0 += __shfl_xor(pr0, m, 64); pr1 += __shfl_xor(pr1, m, 64);
      pr2 += __shfl_xor(pr2, m, 64); pr3 += __shfl_xor(pr3, m, 64);
    }
    if ((u & 7) == 0) {
      if (nb + 0 < N_NODES) { el[(nb + 0) * 4 + h] = pl0; er[(nb + 0) * 4 + h] = pr0; }
      if (nb + 1 < N_NODES) { el[(nb + 1) * 4 + h] = pl1; er[(nb + 1) * 4 + h] = pr1; }
      if (nb + 2 < N_NODES) { el[(nb + 2) * 4 + h] = pl2; er[(nb + 2) * 4 + h] = pr2; }
      if (nb + 3 < N_NODES) { el[(nb + 3) * 4 + h] = pl3; er[(nb + 3) * 4 + h] = pr3; }
    }
    __syncthreads();
  }
}

// ---------------------------------------------------------------------------
// CSR build: count -> 2-level exclusive scan -> scatter (atomicSub reuses cnt)
// ---------------------------------------------------------------------------
__global__ void k_count(const int* __restrict__ dst, int* __restrict__ cnt) {
  int e = blockIdx.x * 256 + threadIdx.x;
  if (e < N_EDGES) atomicAdd(&cnt[dst[e]], 1);
}

__global__ void k_scan1(const int* __restrict__ cnt, int* __restrict__ tsum) {
  __shared__ int sh[256];
  int i = blockIdx.x * 256 + threadIdx.x;
  sh[threadIdx.x] = (i < N_NODES) ? cnt[i] : 0;
  __syncthreads();
  for (int s = 128; s > 0; s >>= 1) {
    if (threadIdx.x < s) sh[threadIdx.x] += sh[threadIdx.x + s];
    __syncthreads();
  }
  if (threadIdx.x == 0) tsum[blockIdx.x] = sh[0];
}

__global__ void k_scan2(int* tsum) {
  __shared__ int sh[256];
  int t = threadIdx.x;
  int v = (t < NT_SCAN) ? tsum[t] : 0;
  sh[t] = v;
  __syncthreads();
  for (int s = 1; s < 256; s <<= 1) {
    int add = (t >= s) ? sh[t - s] : 0;
    __syncthreads();
    sh[t] += add;
    __syncthreads();
  }
  if (t < NT_SCAN) tsum[t] = sh[t] - v;  // exclusive
}

__global__ void k_scan3(const int* __restrict__ cnt, const int* __restrict__ tsum,
                        int* __restrict__ off) {
  __shared__ int sh[256];
  int t = threadIdx.x;
  int i = blockIdx.x * 256 + t;
  int v = (i < N_NODES) ? cnt[i] : 0;
  sh[t] = v;
  __syncthreads();
  for (int s = 1; s < 256; s <<= 1) {
    int add = (t >= s) ? sh[t - s] : 0;
    __syncthreads();
    sh[t] += add;
    __syncthreads();
  }
  int excl = sh[t] - v + tsum[blockIdx.x];
  if (i < N_NODES) {
    off[i] = excl;
    if (i == N_NODES - 1) off[N_NODES] = excl + v;
  }
}

__global__ void k_scatter(const int* __restrict__ src, const int* __restrict__ dst,
                          const int* __restrict__ off, int* __restrict__ cnt,
                          int* __restrict__ srcbuf) {
  int e = blockIdx.x * 256 + threadIdx.x;
  if (e >= N_EDGES) return;
  int d = dst[e];
  int pos = atomicSub(&cnt[d], 1) - 1;
  srcbuf[off[d] + pos] = src[e];
}

// ---------------------------------------------------------------------------
// Kernel E: per-node online edge-softmax + aggregation + ELU + fc_w dot.
// One wave per dst node. lane l: cols 2l,2l+1 (head h=l>>4). Writes scalar p[v].
// ---------------------------------------------------------------------------
__global__ __launch_bounds__(256) void k_aggregate(
    const float* __restrict__ feat, const float* __restrict__ el,
    const float* __restrict__ er, const int* __restrict__ off,
    const int* __restrict__ srcbuf, const float* __restrict__ bias,
    const float* __restrict__ fc_w, float* __restrict__ pbuf) {
  int gid = blockIdx.x * blockDim.x + threadIdx.x;
  int v = gid >> 6;
  if (v >= N_NODES) return;
  int lane = threadIdx.x & 63;
  int h = lane >> 4;
  int c0 = lane * 2;

  float erv = er[v * 4 + h];
  int start = off[v], end = off[v + 1];
  float m = -INFINITY, sum = 0.f, acc0 = 0.f, acc1 = 0.f;

  if (end > start) {
    int s = srcbuf[start];
    float els = el[s * 4 + h];
    float2 f = *(const float2*)&feat[(size_t)s * 128 + c0];
    for (int i = start; i < end; ++i) {
      int s2 = (i + 1 < end) ? srcbuf[i + 1] : s;     // prefetch next edge
      float els2 = el[s2 * 4 + h];
      float2 f2 = *(const float2*)&feat[(size_t)s2 * 128 + c0];

      float e = els + erv;
      e = (e > 0.f) ? e : NEG_SLOPE * e;
      float mn = fmaxf(m, e);
      float scale = __expf(m - mn);    // exp(-inf)=0 on first iter
      float p = __expf(e - mn);
      sum = sum * scale + p;
      acc0 = acc0 * scale + f.x * p;
      acc1 = acc1 * scale + f.y * p;
      m = mn;
      els = els2;
      f = f2;
      s = s2;
    }
  }
  float inv = (end > start) ? 1.f / sum : 0.f;
  float r0 = acc0 * inv + bias[c0];
  float r1 = acc1 * inv + bias[c0 + 1];
  r0 = (r0 > 0.f) ? r0 : __expf(r0) - 1.f;   // ELU
  r1 = (r1 > 0.f) ? r1 : __expf(r1) - 1.f;
  float p = r0 * fc_w[c0] + r1 * fc_w[c0 + 1];
#pragma unroll
  for (int mk = 1; mk < 64; mk <<= 1) p += __shfl_xor(p, mk, 64);
  if (lane == 0) pbuf[v] = p;
}

// ---------------------------------------------------------------------------
// Kernel F: per-graph segment mean (graph_ids sorted) + sigmoid
// ---------------------------------------------------------------------------
__global__ void k_pool(const float* __restrict__ pbuf, const int* __restrict__ gids,
                       const float* __restrict__ fc_b, float* __restrict__ y) {
  int g = blockIdx.x;
  int a = 0, b = N_NODES;
  while (a < b) { int mid = (a + b) >> 1; if (gids[mid] < g) a = mid + 1; else b = mid; }
  int lo = a;
  b = N_NODES;
  while (a < b) { int mid = (a + b) >> 1; if (gids[mid] < g + 1) a = mid + 1; else b = mid; }
  int hi = a;

  float s = 0.f;
  for (int i = lo + threadIdx.x; i < hi; i += blockDim.x) s += pbuf[i];
  __shared__ float sh[256];
  sh[threadIdx.x] = s;
  __syncthreads();
  for (int st = 128; st > 0; st >>= 1) {
    if (threadIdx.x < st) sh[threadIdx.x] += sh[threadIdx.x + st];
    __syncthreads();
  }
  if (threadIdx.x == 0) {
    float cnt = (float)(hi - lo);
    float hg = sh[0] / cnt;
    float x = hg + fc_b[0];
    y[g] = 1.f / (1.f + expf(-x));
  }
}

// ---------------------------------------------------------------------------
extern "C" void kernel_launch(void* const* d_in, const int* in_sizes, int n_in,
                              void* d_out, int out_size, void* d_ws, size_t ws_size,
                              hipStream_t stream) {
  const float* features = (const float*)d_in[0];
  const int* src = (const int*)d_in[1];
  const int* dst = (const int*)d_in[2];
  const int* gids = (const int*)d_in[3];
  const float* W = (const float*)d_in[4];
  const float* attn_l = (const float*)d_in[5];
  const float* attn_r = (const float*)d_in[6];
  const float* bias = (const float*)d_in[7];
  const float* fc_w = (const float*)d_in[8];
  const float* fc_b = (const float*)d_in[9];

  float* ws = (float*)d_ws;
  float* feat = ws + OFS_FEAT;
  float* el = ws + OFS_EL;
  float* er = ws + OFS_ER;
  float* pbuf = ws + OFS_P;
  int* cnt = (int*)d_ws + OFS_CNT;
  int* off = (int*)d_ws + OFS_OFF;
  int* tsum = (int*)d_ws + OFS_TS;
  int* srcbuf = (int*)d_ws + OFS_SRC;

  hipMemsetAsync(cnt, 0, N_NODES * sizeof(int), stream);

  k_gemm<<<512, 256, 0, stream>>>(features, W, attn_l, attn_r, feat, el, er);
  k_count<<<(N_EDGES + 255) / 256, 256, 0, stream>>>(dst, cnt);
  k_scan1<<<NT_SCAN, 256, 0, stream>>>(cnt, tsum);
  k_scan2<<<1, 256, 0, stream>>>(tsum);
  k_scan3<<<NT_SCAN, 256, 0, stream>>>(cnt, tsum, off);
  k_scatter<<<(N_EDGES + 255) / 256, 256, 0, stream>>>(src, dst, off, cnt, srcbuf);
  k_aggregate<<<(N_NODES * 64) / 256 + 1, 256, 0, stream>>>(feat, el, er, off, srcbuf,
                                                            bias, fc_w, pbuf);
  k_pool<<<N_GRAPHS, 256, 0, stream>>>(pbuf, gids, fc_b, (float*)d_out);
}